// Round 1
// baseline (1295.408 us; speedup 1.0000x reference)
//
#include <hip/hip_runtime.h>

// Problem constants
#define BATCH 4
#define CH    64
#define HH    64
#define WW    64
#define LL    4096          // HH*WW
#define SPLITS 4
#define RPS   1024          // LL/SPLITS
#define BM    128           // r tile
#define BN    128           // l tile
#define BK    64            // k tile (= CH; one (i,j) offset per k-tile)

// Workspace layout (float words)
//   ssq_rs : [B*L]            @ 0
//   ssq_lr : [B*L]            @ 16384
//   invn_rs: [B*L]            @ 32768
//   invn_lr: [B*L]            @ 49152
//   pmax   : [B*SPLITS*L]     @ 65536
//   parg   : [B*SPLITS*L] int @ 131072
//   arg    : [B*L] int        @ 196608
#define WS_SSQ_RS 0
#define WS_SSQ_LR 16384
#define WS_INV_RS 32768
#define WS_INV_LR 49152
#define WS_PMAX   65536
#define WS_PARG   131072
#define WS_ARG    196608

// -------- 1) channel sum-of-squares per position (both inputs) --------
__global__ void k_ssq(const float* __restrict__ lrsr,
                      const float* __restrict__ refsr,
                      float* __restrict__ ws) {
    int t = blockIdx.x * 256 + threadIdx.x;      // 0..B*L-1
    int b = t >> 12;
    int r = t & (LL - 1);
    const float* pl = lrsr + (size_t)b * CH * LL + r;
    const float* pr = refsr + (size_t)b * CH * LL + r;
    float sl = 0.f, sr = 0.f;
    #pragma unroll 8
    for (int c = 0; c < CH; ++c) {
        float a = pl[c * LL]; sl += a * a;
        float d = pr[c * LL]; sr += d * d;
    }
    ws[WS_SSQ_RS + t] = sr;
    ws[WS_SSQ_LR + t] = sl;
}

// -------- 2) 3x3 box-sum of ssq (zero pad) -> 1/max(norm,eps) --------
__global__ void k_inv(float* __restrict__ ws) {
    int t = blockIdx.x * 256 + threadIdx.x;      // 0..B*L-1
    int b = t >> 12;
    int r = t & (LL - 1);
    int y = r >> 6, x = r & 63;
    float srs = 0.f, slr = 0.f;
    for (int di = -1; di <= 1; ++di) {
        int yy = y + di;
        if ((unsigned)yy >= (unsigned)HH) continue;
        for (int dj = -1; dj <= 1; ++dj) {
            int xx = x + dj;
            if ((unsigned)xx >= (unsigned)WW) continue;
            int idx = b * LL + yy * WW + xx;
            srs += ws[WS_SSQ_RS + idx];
            slr += ws[WS_SSQ_LR + idx];
        }
    }
    ws[WS_INV_RS + t] = 1.f / fmaxf(sqrtf(srs), 1e-12f);
    ws[WS_INV_LR + t] = 1.f / fmaxf(sqrtf(slr), 1e-12f);
}

// -------- 3) fused corr GEMM + running max/argmax over r --------
// A[r][k] = refsr patch element, B[k][l] = lrsr patch element.
// K is reordered as k = q*64 + c (q = 3x3 offset index) so each staged
// k-row has a fixed (i,j): staging is a masked contiguous copy.
__global__ __launch_bounds__(256, 2)
void k_corrmax(const float* __restrict__ lrsr,
               const float* __restrict__ refsr,
               float* __restrict__ ws) {
    __shared__ float As[BK][BM];   // [c][r_local]
    __shared__ float Bs[BK][BN];   // [c][l_local]

    int tid = threadIdx.x;
    int b   = blockIdx.z;
    int l0  = blockIdx.x * BN;
    int rbs = blockIdx.y * RPS;

    const float* xr = refsr + (size_t)b * CH * LL;
    const float* xl = lrsr  + (size_t)b * CH * LL;
    const float* invn_rs = ws + WS_INV_RS + b * LL;

    int tx = tid & 15;        // l direction
    int ty = tid >> 4;        // r direction

    float run_m = -1e30f;     // running max (only meaningful for tid<128)
    int   run_a = 0;

    for (int rt = 0; rt < RPS / BM; ++rt) {
        int r0 = rbs + rt * BM;
        float acc[8][8];
        #pragma unroll
        for (int u = 0; u < 8; ++u)
            #pragma unroll
            for (int v = 0; v < 8; ++v) acc[u][v] = 0.f;

        for (int q = 0; q < 9; ++q) {
            int i = q / 3 - 1;      // -1..1
            int j = q % 3 - 1;
            int off = i * WW + j;
            __syncthreads();        // protect As/Bs (prev k-loop / reduction scratch)
            // stage As (refsr) and Bs (lrsr): 8192 elements each
            #pragma unroll 4
            for (int it = 0; it < 32; ++it) {
                int idx = tid + it * 256;
                int row = idx >> 7;          // c
                int col = idx & 127;
                {
                    int r = r0 + col;
                    int ry = (r >> 6) + i, rx = (r & 63) + j;
                    float v = 0.f;
                    if ((unsigned)ry < (unsigned)HH && (unsigned)rx < (unsigned)WW)
                        v = xr[row * LL + r + off];
                    As[row][col] = v;
                }
                {
                    int l = l0 + col;
                    int ly = (l >> 6) + i, lx = (l & 63) + j;
                    float v = 0.f;
                    if ((unsigned)ly < (unsigned)HH && (unsigned)lx < (unsigned)WW)
                        v = xl[row * LL + l + off];
                    Bs[row][col] = v;
                }
            }
            __syncthreads();
            #pragma unroll 8
            for (int k = 0; k < BK; ++k) {
                float4 a0 = *(const float4*)&As[k][ty * 8];
                float4 a1 = *(const float4*)&As[k][ty * 8 + 4];
                float4 b0 = *(const float4*)&Bs[k][tx * 8];
                float4 b1 = *(const float4*)&Bs[k][tx * 8 + 4];
                float a[8] = {a0.x, a0.y, a0.z, a0.w, a1.x, a1.y, a1.z, a1.w};
                float bb[8] = {b0.x, b0.y, b0.z, b0.w, b1.x, b1.y, b1.z, b1.w};
                #pragma unroll
                for (int u = 0; u < 8; ++u)
                    #pragma unroll
                    for (int v = 0; v < 8; ++v)
                        acc[u][v] += a[u] * bb[v];
            }
        }

        // scale by invn_rs[r], per-thread max over u, then block reduce per l
        __syncthreads();                       // done reading As -> reuse as scratch
        float* redm = (float*)As;              // [16][128]
        int*   redi = (int*)(redm + 16 * 128); // [16][128] (fits in As)
        #pragma unroll
        for (int v = 0; v < 8; ++v) {
            float bm = -1e30f; int ba = 0;
            #pragma unroll
            for (int u = 0; u < 8; ++u) {
                int r = r0 + ty * 8 + u;
                float val = acc[u][v] * invn_rs[r];
                if (val > bm) { bm = val; ba = r; }   // u ascending -> first index
            }
            redm[ty * 128 + tx * 8 + v] = bm;
            redi[ty * 128 + tx * 8 + v] = ba;
        }
        __syncthreads();
        if (tid < 128) {
            float bm = run_m; int ba = run_a;
            for (int t = 0; t < 16; ++t) {            // t ascending = r ascending
                float v = redm[t * 128 + tid];
                if (v > bm) { bm = v; ba = redi[t * 128 + tid]; }
            }
            run_m = bm; run_a = ba;
        }
        // next iteration's first __syncthreads() protects redm before restaging
    }

    if (tid < 128) {
        int l = l0 + tid;
        int o = (b * SPLITS + blockIdx.y) * LL + l;
        ws[WS_PMAX + o] = run_m;
        ((int*)ws)[WS_PARG + o] = run_a;
    }
}

// -------- 4) reduce over splits -> s output + final argmax --------
__global__ void k_reduce(float* __restrict__ ws, float* __restrict__ out) {
    int t = blockIdx.x * 256 + threadIdx.x;   // 0..B*L-1
    int b = t >> 12;
    int l = t & (LL - 1);
    float bm = -1e30f; int ba = 0;
    for (int s = 0; s < SPLITS; ++s) {        // s ascending = r ascending
        int o = (b * SPLITS + s) * LL + l;
        float v = ws[WS_PMAX + o];
        if (v > bm) { bm = v; ba = ((int*)ws)[WS_PARG + o]; }
    }
    out[t] = bm * ws[WS_INV_LR + t];          // s: [B,1,H,W] flat
    ((int*)ws)[WS_ARG + t] = ba;
}

// -------- 5) gather from ref via argmax + fold(3x3, pad 1) --------
__global__ void k_fold(const float* __restrict__ ref,
                       const float* __restrict__ ws,
                       float* __restrict__ out) {
    int t = blockIdx.x * 256 + threadIdx.x;   // 0..B*C*L-1
    int b = t >> 18;
    int c = (t >> 12) & 63;
    int yx = t & (LL - 1);
    int y = yx >> 6, x = yx & 63;
    const int* ab = ((const int*)ws) + WS_ARG + b * LL;
    const float* rb = ref + (size_t)b * CH * LL + c * LL;
    float s = 0.f;
    #pragma unroll
    for (int i = 0; i < 3; ++i) {
        int yp = y + 1 - i;
        if ((unsigned)yp >= (unsigned)HH) continue;
        #pragma unroll
        for (int j = 0; j < 3; ++j) {
            int xp = x + 1 - j;
            if ((unsigned)xp >= (unsigned)WW) continue;
            int r = ab[yp * WW + xp];
            int ry = (r >> 6) + i - 1;
            int rx = (r & 63) + j - 1;
            if ((unsigned)ry < (unsigned)HH && (unsigned)rx < (unsigned)WW)
                s += rb[ry * WW + rx];
        }
    }
    out[BATCH * LL + t] = s;                  // trans after s (16384 floats)
}

extern "C" void kernel_launch(void* const* d_in, const int* in_sizes, int n_in,
                              void* d_out, int out_size, void* d_ws, size_t ws_size,
                              hipStream_t stream) {
    const float* lrsr = (const float*)d_in[0];
    const float* refsr = (const float*)d_in[1];
    const float* ref  = (const float*)d_in[2];
    float* out = (float*)d_out;
    float* ws  = (float*)d_ws;

    k_ssq<<<dim3(BATCH * LL / 256), dim3(256), 0, stream>>>(lrsr, refsr, ws);
    k_inv<<<dim3(BATCH * LL / 256), dim3(256), 0, stream>>>(ws);
    k_corrmax<<<dim3(LL / BN, SPLITS, BATCH), dim3(256), 0, stream>>>(lrsr, refsr, ws);
    k_reduce<<<dim3(BATCH * LL / 256), dim3(256), 0, stream>>>(ws, out);
    k_fold<<<dim3(BATCH * CH * LL / 256), dim3(256), 0, stream>>>(ref, ws, out);
}

// Round 2
// 1005.019 us; speedup vs baseline: 1.2889x; 1.2889x over previous
//
#include <hip/hip_runtime.h>

// Problem constants
#define BATCH 4
#define CH    64
#define HH    64
#define WW    64
#define LL    4096          // HH*WW
#define SPLITS 4
#define RPS   1024          // LL/SPLITS
#define BM    128           // r tile
#define BN    128           // l tile
#define BK    32            // k tile (half of CH per stage; 32KiB LDS -> 4 blocks/CU)

// Workspace layout (float words)
#define WS_SSQ_RS 0
#define WS_SSQ_LR 16384
#define WS_INV_RS 32768
#define WS_INV_LR 49152
#define WS_PMAX   65536
#define WS_PARG   131072
#define WS_ARG    196608

// -------- 1) channel sum-of-squares per position (both inputs) --------
__global__ void k_ssq(const float* __restrict__ lrsr,
                      const float* __restrict__ refsr,
                      float* __restrict__ ws) {
    int t = blockIdx.x * 256 + threadIdx.x;      // 0..B*L-1
    int b = t >> 12;
    int r = t & (LL - 1);
    const float* pl = lrsr + (size_t)b * CH * LL + r;
    const float* pr = refsr + (size_t)b * CH * LL + r;
    float sl = 0.f, sr = 0.f;
    #pragma unroll 8
    for (int c = 0; c < CH; ++c) {
        float a = pl[c * LL]; sl += a * a;
        float d = pr[c * LL]; sr += d * d;
    }
    ws[WS_SSQ_RS + t] = sr;
    ws[WS_SSQ_LR + t] = sl;
}

// -------- 2) 3x3 box-sum of ssq (zero pad) -> 1/max(norm,eps) --------
__global__ void k_inv(float* __restrict__ ws) {
    int t = blockIdx.x * 256 + threadIdx.x;      // 0..B*L-1
    int b = t >> 12;
    int r = t & (LL - 1);
    int y = r >> 6, x = r & 63;
    float srs = 0.f, slr = 0.f;
    for (int di = -1; di <= 1; ++di) {
        int yy = y + di;
        if ((unsigned)yy >= (unsigned)HH) continue;
        for (int dj = -1; dj <= 1; ++dj) {
            int xx = x + dj;
            if ((unsigned)xx >= (unsigned)WW) continue;
            int idx = b * LL + yy * WW + xx;
            srs += ws[WS_SSQ_RS + idx];
            slr += ws[WS_SSQ_LR + idx];
        }
    }
    ws[WS_INV_RS + t] = 1.f / fmaxf(sqrtf(srs), 1e-12f);
    ws[WS_INV_LR + t] = 1.f / fmaxf(sqrtf(slr), 1e-12f);
}

// -------- 3) fused corr GEMM + running max/argmax over r --------
// Thread (tx,ty) owns rows r0 + ty*4+{0..3} and r0+64 + ty*4+{0..3},
// cols l0 + tx*4+{0..3} and l0+64 + tx*4+{0..3}  (2x float4 at stride 64:
// B-fragment read covers words 0..63 across 16 lanes -> 2-way bank alias = free).
__global__ __launch_bounds__(256, 4)
void k_corrmax(const float* __restrict__ lrsr,
               const float* __restrict__ refsr,
               float* __restrict__ ws) {
    __shared__ float As[BK][BM];   // 16 KiB
    __shared__ float Bs[BK][BN];   // 16 KiB

    int tid = threadIdx.x;
    int b   = blockIdx.z;
    int l0  = blockIdx.x * BN;
    int rbs = blockIdx.y * RPS;

    const float* xr = refsr + (size_t)b * CH * LL;
    const float* xl = lrsr  + (size_t)b * CH * LL;
    const float* invn_rs = ws + WS_INV_RS + b * LL;

    int tx = tid & 15;        // l direction
    int ty = tid >> 4;        // r direction
    int col  = tid & 127;     // staging column (loop-invariant per thread)
    int row0 = tid >> 7;      // staging row parity (0/1)

    float run_m = -1e30f;     // running max (only meaningful for tid<128)
    int   run_a = 0;

    for (int rt = 0; rt < RPS / BM; ++rt) {
        int r0 = rbs + rt * BM;
        float acc[8][8];
        #pragma unroll
        for (int u = 0; u < 8; ++u)
            #pragma unroll
            for (int v = 0; v < 8; ++v) acc[u][v] = 0.f;

        for (int q = 0; q < 9; ++q) {
            int i = q / 3 - 1;      // -1..1
            int j = q % 3 - 1;
            int off = i * WW + j;
            // per-q staging masks + clamped base addresses (branchless loads)
            int rr = r0 + col;
            bool okA = ((unsigned)((rr >> 6) + i) < (unsigned)HH) &&
                       ((unsigned)((rr & 63) + j) < (unsigned)WW);
            int lcl = l0 + col;
            bool okB = ((unsigned)((lcl >> 6) + i) < (unsigned)HH) &&
                       ((unsigned)((lcl & 63) + j) < (unsigned)WW);
            const float* pA = xr + (okA ? rr + off : 0);
            const float* pB = xl + (okB ? lcl + off : 0);

            for (int h = 0; h < 2; ++h) {
                const float* pAh = pA + (h * BK + row0) * LL;
                const float* pBh = pB + (h * BK + row0) * LL;
                __syncthreads();        // protect As/Bs from previous readers
                #pragma unroll
                for (int it = 0; it < 16; ++it) {
                    int r = row0 + it * 2;          // 0..31
                    float va = pAh[it * 2 * LL];
                    float vb = pBh[it * 2 * LL];
                    As[r][col] = okA ? va : 0.f;
                    Bs[r][col] = okB ? vb : 0.f;
                }
                __syncthreads();
                #pragma unroll 8
                for (int k = 0; k < BK; ++k) {
                    float4 a0 = *(const float4*)&As[k][ty * 4];
                    float4 a1 = *(const float4*)&As[k][ty * 4 + 64];
                    float4 b0 = *(const float4*)&Bs[k][tx * 4];
                    float4 b1 = *(const float4*)&Bs[k][tx * 4 + 64];
                    float a[8]  = {a0.x, a0.y, a0.z, a0.w, a1.x, a1.y, a1.z, a1.w};
                    float bb[8] = {b0.x, b0.y, b0.z, b0.w, b1.x, b1.y, b1.z, b1.w};
                    #pragma unroll
                    for (int u = 0; u < 8; ++u)
                        #pragma unroll
                        for (int v = 0; v < 8; ++v)
                            acc[u][v] += a[u] * bb[v];
                }
            }
        }

        // scale by invn_rs[r], per-thread max over u, then block reduce per l
        __syncthreads();                       // all readers of As done -> scratch
        float* redm = (float*)As;              // [16][128]
        int*   redi = (int*)&As[0][0] + 2048;  // [16][128]
        #pragma unroll
        for (int v = 0; v < 8; ++v) {
            int lcol = tx * 4 + (v & 3) + ((v >> 2) << 6);
            float bm = -1e30f; int ba = 0;
            #pragma unroll
            for (int u = 0; u < 8; ++u) {
                int r = r0 + ty * 4 + (u & 3) + ((u >> 2) << 6);  // ascending in u
                float val = acc[u][v] * invn_rs[r];
                if (val > bm) { bm = val; ba = r; }
            }
            redm[ty * 128 + lcol] = bm;
            redi[ty * 128 + lcol] = ba;
        }
        __syncthreads();
        if (tid < 128) {
            float bm = run_m; int ba = run_a;
            for (int t = 0; t < 16; ++t) {
                float v = redm[t * 128 + tid];
                int   a = redi[t * 128 + tid];
                if (v > bm || (v == bm && a < ba)) { bm = v; ba = a; }  // smallest r on tie
            }
            run_m = bm; run_a = ba;
        }
        // next rt's first stage __syncthreads() protects scratch
    }

    if (tid < 128) {
        int l = l0 + tid;
        int o = (b * SPLITS + blockIdx.y) * LL + l;
        ws[WS_PMAX + o] = run_m;
        ((int*)ws)[WS_PARG + o] = run_a;
    }
}

// -------- 4) reduce over splits -> s output + final argmax --------
__global__ void k_reduce(float* __restrict__ ws, float* __restrict__ out) {
    int t = blockIdx.x * 256 + threadIdx.x;   // 0..B*L-1
    int b = t >> 12;
    int l = t & (LL - 1);
    float bm = -1e30f; int ba = 0;
    for (int s = 0; s < SPLITS; ++s) {        // s ascending = r ascending (disjoint ranges)
        int o = (b * SPLITS + s) * LL + l;
        float v = ws[WS_PMAX + o];
        if (v > bm) { bm = v; ba = ((int*)ws)[WS_PARG + o]; }
    }
    out[t] = bm * ws[WS_INV_LR + t];          // s: [B,1,H,W] flat
    ((int*)ws)[WS_ARG + t] = ba;
}

// -------- 5) gather from ref via argmax + fold(3x3, pad 1) --------
__global__ void k_fold(const float* __restrict__ ref,
                       const float* __restrict__ ws,
                       float* __restrict__ out) {
    int t = blockIdx.x * 256 + threadIdx.x;   // 0..B*C*L-1
    int b = t >> 18;
    int c = (t >> 12) & 63;
    int yx = t & (LL - 1);
    int y = yx >> 6, x = yx & 63;
    const int* ab = ((const int*)ws) + WS_ARG + b * LL;
    const float* rb = ref + (size_t)b * CH * LL + c * LL;
    float s = 0.f;
    #pragma unroll
    for (int i = 0; i < 3; ++i) {
        int yp = y + 1 - i;
        if ((unsigned)yp >= (unsigned)HH) continue;
        #pragma unroll
        for (int j = 0; j < 3; ++j) {
            int xp = x + 1 - j;
            if ((unsigned)xp >= (unsigned)WW) continue;
            int r = ab[yp * WW + xp];
            int ry = (r >> 6) + i - 1;
            int rx = (r & 63) + j - 1;
            if ((unsigned)ry < (unsigned)HH && (unsigned)rx < (unsigned)WW)
                s += rb[ry * WW + rx];
        }
    }
    out[BATCH * LL + t] = s;                  // trans after s (16384 floats)
}

extern "C" void kernel_launch(void* const* d_in, const int* in_sizes, int n_in,
                              void* d_out, int out_size, void* d_ws, size_t ws_size,
                              hipStream_t stream) {
    const float* lrsr = (const float*)d_in[0];
    const float* refsr = (const float*)d_in[1];
    const float* ref  = (const float*)d_in[2];
    float* out = (float*)d_out;
    float* ws  = (float*)d_ws;

    k_ssq<<<dim3(BATCH * LL / 256), dim3(256), 0, stream>>>(lrsr, refsr, ws);
    k_inv<<<dim3(BATCH * LL / 256), dim3(256), 0, stream>>>(ws);
    k_corrmax<<<dim3(LL / BN, SPLITS, BATCH), dim3(256), 0, stream>>>(lrsr, refsr, ws);
    k_reduce<<<dim3(BATCH * LL / 256), dim3(256), 0, stream>>>(ws, out);
    k_fold<<<dim3(BATCH * CH * LL / 256), dim3(256), 0, stream>>>(ref, ws, out);
}

// Round 3
// 464.217 us; speedup vs baseline: 2.7905x; 2.1650x over previous
//
#include <hip/hip_runtime.h>

// Problem constants
#define BATCH 4
#define CH    64
#define HH    64
#define WW    64
#define LL    4096          // HH*WW
#define SPLITS 4
#define RPS   1024          // LL/SPLITS
#define BM    128           // r tile
#define BN    128           // l tile

// LDS tile row stride in ushort elems: 3 comps * 32 k + 16 pad = 112 (224 B)
#define RSTRIDE 112

// Workspace layout (float words)
#define WS_SSQ_RS 0
#define WS_SSQ_LR 16384
#define WS_INV_RS 32768
#define WS_INV_LR 49152
#define WS_PMAX   65536
#define WS_PARG   131072
#define WS_ARG    196608

typedef __attribute__((ext_vector_type(8))) short short8b;
typedef __attribute__((ext_vector_type(4))) short short4b;
typedef __attribute__((ext_vector_type(4))) float f32x4;

// -------- 1) channel sum-of-squares per position (both inputs) --------
__global__ void k_ssq(const float* __restrict__ lrsr,
                      const float* __restrict__ refsr,
                      float* __restrict__ ws) {
    int t = blockIdx.x * 256 + threadIdx.x;      // 0..B*L-1
    int b = t >> 12;
    int r = t & (LL - 1);
    const float* pl = lrsr + (size_t)b * CH * LL + r;
    const float* pr = refsr + (size_t)b * CH * LL + r;
    float sl = 0.f, sr = 0.f;
    #pragma unroll 8
    for (int c = 0; c < CH; ++c) {
        float a = pl[c * LL]; sl += a * a;
        float d = pr[c * LL]; sr += d * d;
    }
    ws[WS_SSQ_RS + t] = sr;
    ws[WS_SSQ_LR + t] = sl;
}

// -------- 2) 3x3 box-sum of ssq (zero pad) -> 1/max(norm,eps) --------
__global__ void k_inv(float* __restrict__ ws) {
    int t = blockIdx.x * 256 + threadIdx.x;      // 0..B*L-1
    int b = t >> 12;
    int r = t & (LL - 1);
    int y = r >> 6, x = r & 63;
    float srs = 0.f, slr = 0.f;
    for (int di = -1; di <= 1; ++di) {
        int yy = y + di;
        if ((unsigned)yy >= (unsigned)HH) continue;
        for (int dj = -1; dj <= 1; ++dj) {
            int xx = x + dj;
            if ((unsigned)xx >= (unsigned)WW) continue;
            int idx = b * LL + yy * WW + xx;
            srs += ws[WS_SSQ_RS + idx];
            slr += ws[WS_SSQ_LR + idx];
        }
    }
    ws[WS_INV_RS + t] = 1.f / fmaxf(sqrtf(srs), 1e-12f);
    ws[WS_INV_LR + t] = 1.f / fmaxf(sqrtf(slr), 1e-12f);
}

// -------- 3) MFMA corr GEMM (bf16 3-way split, 6 products) + max/argmax ----
// corr[r][l] = sum_k A[r][k]*B[k][l], fp32-faithful via x=x0+x1+x2 bf16 split,
// kept products: 00,01,10,11,02,20 (dropped terms <= 2^-24 rel).
// LDS layout per tile: [pos][comp][k] ushort, row stride 112 elems (224 B),
// 8-k slot swizzle: slot' = (k>>3) ^ ((pos>>2)&3)  -> 2-way (free) banks for
// both b64 staging writes and b128 fragment reads.
__global__ __launch_bounds__(256, 2)
void k_corrmax(const float* __restrict__ lrsr,
               const float* __restrict__ refsr,
               float* __restrict__ ws) {
    __shared__ __align__(16) unsigned short As[BM * RSTRIDE];  // 28 KiB
    __shared__ __align__(16) unsigned short Bs[BN * RSTRIDE];  // 28 KiB

    int tid  = threadIdx.x;
    int b    = blockIdx.z;
    int l0   = blockIdx.x * BN;
    int rbs  = blockIdx.y * RPS;

    const float* xr = refsr + (size_t)b * CH * LL;
    const float* xl = lrsr  + (size_t)b * CH * LL;
    const float* invn_rs = ws + WS_INV_RS + b * LL;

    int lane = tid & 63;
    int wid  = tid >> 6;        // wave id 0..3
    int wr   = wid >> 1;        // wave row (r half)
    int wc   = wid & 1;         // wave col (l half)
    int ln   = lane & 15;
    int g    = lane >> 4;       // k-group 0..3

    // staging decomposition: p = position 0..63 (+64), kp = channel octet 0..3
    int p  = tid & 63;
    int kp = tid >> 6;

    // fragment LDS base addrs (elems), +c*32 added per comp at read time
    int abase[4], bbase[4];
    #pragma unroll
    for (int mf = 0; mf < 4; ++mf) {
        int rloc = wr * 64 + mf * 16 + ln;
        abase[mf] = rloc * RSTRIDE + ((g ^ ((rloc >> 2) & 3)) << 3);
        int lloc = wc * 64 + mf * 16 + ln;
        bbase[mf] = lloc * RSTRIDE + ((g ^ ((lloc >> 2) & 3)) << 3);
    }

    float run_m = -1e30f;       // running max (tid<128 only)
    int   run_a = 0;

    for (int rt = 0; rt < RPS / BM; ++rt) {
        int r0 = rbs + rt * BM;

        f32x4 acc[4][4];
        #pragma unroll
        for (int mf = 0; mf < 4; ++mf)
            #pragma unroll
            for (int nf = 0; nf < 4; ++nf)
                acc[mf][nf] = (f32x4){0.f, 0.f, 0.f, 0.f};

        for (int q = 0; q < 9; ++q) {
            int i = q / 3 - 1;
            int j = q % 3 - 1;
            int off = i * WW + j;
            // per-thread masks & clamped bases for both position halves
            bool okA[2], okB[2];
            const float* gA[2];
            const float* gB[2];
            #pragma unroll
            for (int rh = 0; rh < 2; ++rh) {
                int pp = p + rh * 64;
                int rpos = r0 + pp;
                okA[rh] = ((unsigned)((rpos >> 6) + i) < (unsigned)HH) &&
                          ((unsigned)((rpos & 63) + j) < (unsigned)WW);
                gA[rh] = xr + (okA[rh] ? rpos + off : 0) + kp * 8 * LL;
                int lpos = l0 + pp;
                okB[rh] = ((unsigned)((lpos >> 6) + i) < (unsigned)HH) &&
                          ((unsigned)((lpos & 63) + j) < (unsigned)WW);
                gB[rh] = xl + (okB[rh] ? lpos + off : 0) + kp * 8 * LL;
            }

            for (int h = 0; h < 2; ++h) {
                int choff = h * 32 * LL;
                __syncthreads();   // previous readers of As/Bs done
                // ---- stage A and B: 32 ch x 128 pos x 3 comps ----
                #pragma unroll
                for (int rh = 0; rh < 2; ++rh) {
                    int pp = p + rh * 64;
                    int rowbase = pp * RSTRIDE + ((kp ^ ((pp >> 2) & 3)) << 3);
                    #pragma unroll
                    for (int side = 0; side < 2; ++side) {
                        const float* gp = (side ? gB[rh] : gA[rh]) + choff;
                        bool ok = side ? okB[rh] : okA[rh];
                        unsigned short* S = side ? Bs : As;
                        #pragma unroll
                        for (int i4 = 0; i4 < 2; ++i4) {
                            float v[4];
                            #pragma unroll
                            for (int c4 = 0; c4 < 4; ++c4)
                                v[c4] = gp[(i4 * 4 + c4) * LL];
                            short4b w0, w1, w2;
                            #pragma unroll
                            for (int c4 = 0; c4 < 4; ++c4) {
                                float x = ok ? v[c4] : 0.f;
                                unsigned u0 = __float_as_uint(x);
                                float f0 = __uint_as_float(u0 & 0xffff0000u);
                                float r1 = x - f0;
                                unsigned u1 = __float_as_uint(r1);
                                float f1 = __uint_as_float(u1 & 0xffff0000u);
                                float r2 = r1 - f1;
                                w0[c4] = (short)(u0 >> 16);
                                w1[c4] = (short)(u1 >> 16);
                                w2[c4] = (short)(__float_as_uint(r2) >> 16);
                            }
                            int idx = rowbase + i4 * 4;
                            *(short4b*)&S[idx]          = w0;
                            *(short4b*)&S[idx + 32]     = w1;
                            *(short4b*)&S[idx + 64]     = w2;
                        }
                    }
                }
                __syncthreads();
                // ---- fragments + 6-product MFMA ----
                short8b a[4][3], bb[4][3];
                #pragma unroll
                for (int mf = 0; mf < 4; ++mf)
                    #pragma unroll
                    for (int c = 0; c < 3; ++c) {
                        a[mf][c]  = *(const short8b*)&As[abase[mf] + c * 32];
                        bb[mf][c] = *(const short8b*)&Bs[bbase[mf] + c * 32];
                    }
                #pragma unroll
                for (int mf = 0; mf < 4; ++mf)
                    #pragma unroll
                    for (int nf = 0; nf < 4; ++nf) {
                        f32x4 d = acc[mf][nf];
                        d = __builtin_amdgcn_mfma_f32_16x16x32_bf16(a[mf][0], bb[nf][0], d, 0, 0, 0);
                        d = __builtin_amdgcn_mfma_f32_16x16x32_bf16(a[mf][0], bb[nf][1], d, 0, 0, 0);
                        d = __builtin_amdgcn_mfma_f32_16x16x32_bf16(a[mf][1], bb[nf][0], d, 0, 0, 0);
                        d = __builtin_amdgcn_mfma_f32_16x16x32_bf16(a[mf][1], bb[nf][1], d, 0, 0, 0);
                        d = __builtin_amdgcn_mfma_f32_16x16x32_bf16(a[mf][0], bb[nf][2], d, 0, 0, 0);
                        d = __builtin_amdgcn_mfma_f32_16x16x32_bf16(a[mf][2], bb[nf][0], d, 0, 0, 0);
                        acc[mf][nf] = d;
                    }
            }
        }

        // ---- epilogue: scale by invn_rs, max/argmax over this rt's 128 r ----
        // C layout: col = lane&15 (l), row = g*4 + reg (within 16-r frag)
        __syncthreads();                       // all MFMA LDS reads done
        float* sm = (float*)As;                // [2][128]
        int*   si = (int*)((float*)As + 256);  // [2][128]
        #pragma unroll
        for (int nf = 0; nf < 4; ++nf) {
            float bv = -1e30f; int bi = 0;
            #pragma unroll
            for (int mf = 0; mf < 4; ++mf) {
                #pragma unroll
                for (int reg = 0; reg < 4; ++reg) {
                    int r = r0 + wr * 64 + mf * 16 + g * 4 + reg;
                    float val = acc[mf][nf][reg] * invn_rs[r];
                    if (val > bv || (val == bv && r < bi)) { bv = val; bi = r; }
                }
            }
            // reduce across lane groups (same l col: lanes ln, ln+16, ln+32, ln+48)
            #pragma unroll
            for (int ofs = 16; ofs < 64; ofs <<= 1) {
                float ov = __shfl_xor(bv, ofs);
                int   oi = __shfl_xor(bi, ofs);
                if (ov > bv || (ov == bv && oi < bi)) { bv = ov; bi = oi; }
            }
            if (g == 0) {
                int col = wc * 64 + nf * 16 + ln;
                sm[wr * 128 + col] = bv;
                si[wr * 128 + col] = bi;
            }
        }
        __syncthreads();
        if (tid < 128) {
            float bm = run_m; int ba = run_a;
            #pragma unroll
            for (int w = 0; w < 2; ++w) {
                float v = sm[w * 128 + tid];
                int   a2 = si[w * 128 + tid];
                if (v > bm || (v == bm && a2 < ba)) { bm = v; ba = a2; }
            }
            run_m = bm; run_a = ba;
        }
        // next rt's first stage barrier protects scratch
    }

    if (tid < 128) {
        int l = l0 + tid;
        int o = (b * SPLITS + blockIdx.y) * LL + l;
        ws[WS_PMAX + o] = run_m;
        ((int*)ws)[WS_PARG + o] = run_a;
    }
}

// -------- 4) reduce over splits -> s output + final argmax --------
__global__ void k_reduce(float* __restrict__ ws, float* __restrict__ out) {
    int t = blockIdx.x * 256 + threadIdx.x;   // 0..B*L-1
    int b = t >> 12;
    int l = t & (LL - 1);
    float bm = -1e30f; int ba = 0;
    for (int s = 0; s < SPLITS; ++s) {        // splits are ascending r ranges
        int o = (b * SPLITS + s) * LL + l;
        float v = ws[WS_PMAX + o];
        int   a = ((int*)ws)[WS_PARG + o];
        if (v > bm || (v == bm && a < ba)) { bm = v; ba = a; }
    }
    out[t] = bm * ws[WS_INV_LR + t];          // s: [B,1,H,W] flat
    ((int*)ws)[WS_ARG + t] = ba;
}

// -------- 5) gather from ref via argmax + fold(3x3, pad 1) --------
__global__ void k_fold(const float* __restrict__ ref,
                       const float* __restrict__ ws,
                       float* __restrict__ out) {
    int t = blockIdx.x * 256 + threadIdx.x;   // 0..B*C*L-1
    int b = t >> 18;
    int c = (t >> 12) & 63;
    int yx = t & (LL - 1);
    int y = yx >> 6, x = yx & 63;
    const int* ab = ((const int*)ws) + WS_ARG + b * LL;
    const float* rb = ref + (size_t)b * CH * LL + c * LL;
    float s = 0.f;
    #pragma unroll
    for (int i = 0; i < 3; ++i) {
        int yp = y + 1 - i;
        if ((unsigned)yp >= (unsigned)HH) continue;
        #pragma unroll
        for (int j = 0; j < 3; ++j) {
            int xp = x + 1 - j;
            if ((unsigned)xp >= (unsigned)WW) continue;
            int r = ab[yp * WW + xp];
            int ry = (r >> 6) + i - 1;
            int rx = (r & 63) + j - 1;
            if ((unsigned)ry < (unsigned)HH && (unsigned)rx < (unsigned)WW)
                s += rb[ry * WW + rx];
        }
    }
    out[BATCH * LL + t] = s;                  // trans after s (16384 floats)
}

extern "C" void kernel_launch(void* const* d_in, const int* in_sizes, int n_in,
                              void* d_out, int out_size, void* d_ws, size_t ws_size,
                              hipStream_t stream) {
    const float* lrsr = (const float*)d_in[0];
    const float* refsr = (const float*)d_in[1];
    const float* ref  = (const float*)d_in[2];
    float* out = (float*)d_out;
    float* ws  = (float*)d_ws;

    k_ssq<<<dim3(BATCH * LL / 256), dim3(256), 0, stream>>>(lrsr, refsr, ws);
    k_inv<<<dim3(BATCH * LL / 256), dim3(256), 0, stream>>>(ws);
    k_corrmax<<<dim3(LL / BN, SPLITS, BATCH), dim3(256), 0, stream>>>(lrsr, refsr, ws);
    k_reduce<<<dim3(BATCH * LL / 256), dim3(256), 0, stream>>>(ws, out);
    k_fold<<<dim3(BATCH * CH * LL / 256), dim3(256), 0, stream>>>(ref, ws, out);
}

// Round 4
// 425.914 us; speedup vs baseline: 3.0415x; 1.0899x over previous
//
#include <hip/hip_runtime.h>

// Problem constants
#define BATCH 4
#define CH    64
#define HH    64
#define WW    64
#define LL    4096          // HH*WW
#define SPLITS 4
#define RPS   1024          // LL/SPLITS
#define BM    128           // r tile
#define BN    128           // l tile
#define NRT   (RPS/BM)      // 8

// LDS tile: per side 128 rows x 96 ushort (3 comps x 32 k), 192 B/row, 24 KB
#define RSTB  192           // row stride bytes
#define BSOFF 24576         // Bs byte offset within LDSB

// Padded pre-split global image Gp[side][b][comp][c8(8)][4356][8ch] (ushort)
#define PAD_L   4356        // 66*66
#define GP_BYTE_BASE 1048576
#define GP_SIDE_STRIDE 6690816   // 4*3*8*4356*8*2
#define GP_B_STRIDE    1672704   // 3*8*4356*8*2
#define GP_COMP_STRIDE 557568    // 8*4356*16
#define GP_TOTAL       13381632 // 2*GP_SIDE_STRIDE

// Workspace layout (float words)
#define WS_SSQ_RS 0
#define WS_SSQ_LR 16384
#define WS_INV_RS 32768
#define WS_INV_LR 49152
#define WS_PMAX   65536
#define WS_PARG   131072
#define WS_ARG    196608

typedef __attribute__((ext_vector_type(8))) short short8b;
typedef __attribute__((ext_vector_type(4))) float f32x4;

__device__ __forceinline__ void gload16(const void* g, void* l) {
    __builtin_amdgcn_global_load_lds(
        (const __attribute__((address_space(1))) unsigned int*)g,
        (__attribute__((address_space(3))) unsigned int*)l, 16, 0, 0);
}

// -------- 0) pre-split: fp32 -> 3 truncated bf16 comps, padded image --------
__global__ void k_split(const float* __restrict__ lrsr,
                        const float* __restrict__ refsr,
                        float* __restrict__ ws) {
    int tid  = threadIdx.x;
    int pos  = blockIdx.x * 256 + tid;          // 0..4095
    int c8   = blockIdx.y;                      // 0..7
    int side = blockIdx.z >> 2;                 // 0 = refsr(A), 1 = lrsr(B)
    int b    = blockIdx.z & 3;
    const float* src = (side ? lrsr : refsr) + (size_t)b * CH * LL + c8 * 8 * LL + pos;
    int ppos = (pos >> 6) * 66 + (pos & 63) + 67;   // (y+1)*66 + (x+1)
    char* dst = (char*)ws + GP_BYTE_BASE + side * GP_SIDE_STRIDE + b * GP_B_STRIDE
              + (size_t)(c8 * PAD_L + ppos) * 16;
    union { unsigned short u[8]; uint4 v; } w0, w1, w2;
    #pragma unroll
    for (int cc = 0; cc < 8; ++cc) {
        float x = src[cc * LL];
        unsigned u0 = __float_as_uint(x);
        float f0 = __uint_as_float(u0 & 0xffff0000u);
        float r1 = x - f0;
        unsigned u1 = __float_as_uint(r1);
        float f1 = __uint_as_float(u1 & 0xffff0000u);
        float r2 = r1 - f1;
        w0.u[cc] = (unsigned short)(u0 >> 16);
        w1.u[cc] = (unsigned short)(u1 >> 16);
        w2.u[cc] = (unsigned short)(__float_as_uint(r2) >> 16);
    }
    *(uint4*)(dst)                      = w0.v;
    *(uint4*)(dst + GP_COMP_STRIDE)     = w1.v;
    *(uint4*)(dst + 2 * GP_COMP_STRIDE) = w2.v;
}

// -------- 1) channel sum-of-squares per position (both inputs) --------
__global__ void k_ssq(const float* __restrict__ lrsr,
                      const float* __restrict__ refsr,
                      float* __restrict__ ws) {
    int t = blockIdx.x * 256 + threadIdx.x;      // 0..B*L-1
    int b = t >> 12;
    int r = t & (LL - 1);
    const float* pl = lrsr + (size_t)b * CH * LL + r;
    const float* pr = refsr + (size_t)b * CH * LL + r;
    float sl = 0.f, sr = 0.f;
    #pragma unroll 8
    for (int c = 0; c < CH; ++c) {
        float a = pl[c * LL]; sl += a * a;
        float d = pr[c * LL]; sr += d * d;
    }
    ws[WS_SSQ_RS + t] = sr;
    ws[WS_SSQ_LR + t] = sl;
}

// -------- 2) 3x3 box-sum of ssq (zero pad) -> 1/max(norm,eps) --------
__global__ void k_inv(float* __restrict__ ws) {
    int t = blockIdx.x * 256 + threadIdx.x;      // 0..B*L-1
    int b = t >> 12;
    int r = t & (LL - 1);
    int y = r >> 6, x = r & 63;
    float srs = 0.f, slr = 0.f;
    for (int di = -1; di <= 1; ++di) {
        int yy = y + di;
        if ((unsigned)yy >= (unsigned)HH) continue;
        for (int dj = -1; dj <= 1; ++dj) {
            int xx = x + dj;
            if ((unsigned)xx >= (unsigned)WW) continue;
            int idx = b * LL + yy * WW + xx;
            srs += ws[WS_SSQ_RS + idx];
            slr += ws[WS_SSQ_LR + idx];
        }
    }
    ws[WS_INV_RS + t] = 1.f / fmaxf(sqrtf(srs), 1e-12f);
    ws[WS_INV_LR + t] = 1.f / fmaxf(sqrtf(slr), 1e-12f);
}

// -------- 3) MFMA corr GEMM, async global_load_lds pipelined --------
__global__ __launch_bounds__(256, 2)
void k_corrmax(float* __restrict__ ws) {
    __shared__ __align__(16) unsigned short LDSB[24576];  // As 24KB | Bs 24KB
    __shared__ float sm[256];
    __shared__ int   si[256];

    int tid  = threadIdx.x;
    int b    = blockIdx.z;
    int l0   = blockIdx.x * BN;
    int rbs  = blockIdx.y * RPS;

    int lane = tid & 63;
    int w    = tid >> 6;        // wave 0..3; waves 0-1 stage A, 2-3 stage B
    int wr   = w >> 1;
    int wc   = w & 1;
    int ln   = lane & 15;
    int g    = lane >> 4;

    const float* invn_rs = ws + WS_INV_RS + b * LL;
    const char* gp  = (const char*)ws + GP_BYTE_BASE + b * GP_B_STRIDE;
    const char* bp  = gp + ((w < 2) ? 0 : GP_SIDE_STRIDE);   // A=refsr(side0), B=lrsr(side1)

    // ---- per-lane staging constants: 12 chunk-issues per wave ----
    int LC[12];     // global byte offset (lane-dependent part)
    int LB[12];     // LDS byte offset (wave-uniform)
    {
        int wm = (w & 1) * 12;              // chunk index within side region
        #pragma unroll
        for (int n = 0; n < 12; ++n) {
            int mm  = wm + n;               // 0..23 within side tile
            int G   = mm * 64 + lane;       // 16B granule index
            int row = G / 12;
            int rem = G - row * 12;
            int comp = rem >> 2;
            int sl   = rem & 3;
            int o    = sl ^ ((row >> 2) & 3);
            LC[n] = (comp * (8 * PAD_L) + o * PAD_L + row + 2 * (row >> 6)) * 16;
            LB[n] = ((w < 2) ? 0 : BSOFF) + mm * 1024;
        }
    }

    // ---- fragment LDS byte offsets ----
    int arow[4], brow[4];
    int swz = (g ^ ((ln >> 2) & 3)) << 4;
    #pragma unroll
    for (int mf = 0; mf < 4; ++mf) {
        arow[mf] = (wr * 64 + mf * 16 + ln) * RSTB + swz;
        brow[mf] = BSOFF + (wc * 64 + mf * 16 + ln) * RSTB + swz;
    }

    int y0B = l0 >> 6;          // B side row base (constant per block)
    int y0A0 = rbs >> 6;

    // issue stage (rt2,q2,h2): 12 async chunk loads
    auto issue = [&](int rt2, int q2, int h2) {
        int i2 = (q2 < 3) ? -1 : ((q2 < 6) ? 0 : 1);
        int j2 = q2 - (i2 + 1) * 3 - 1;
        int y0 = (w < 2) ? (y0A0 + rt2 * 2) : y0B;
        int su = (h2 * (4 * PAD_L) + (y0 + 1 + i2) * 66 + 1 + j2) * 16;
        #pragma unroll
        for (int n = 0; n < 12; ++n)
            gload16(bp + (su + LC[n]), (char*)LDSB + LB[n]);
    };

    float run_m = -1e30f;
    int   run_a = 0;

    issue(0, 0, 0);
    __syncthreads();            // vmcnt(0) drained before barrier

    for (int rt = 0; rt < NRT; ++rt) {
        int r0 = rbs + rt * BM;

        f32x4 acc[4][4];
        #pragma unroll
        for (int mf = 0; mf < 4; ++mf)
            #pragma unroll
            for (int nf = 0; nf < 4; ++nf)
                acc[mf][nf] = (f32x4){0.f, 0.f, 0.f, 0.f};

        for (int q = 0; q < 9; ++q) {
            for (int h = 0; h < 2; ++h) {
                // ---- read fragments of current stage ----
                short8b a[4][3], bb[4][3];
                const char* lc = (const char*)LDSB;
                #pragma unroll
                for (int mf = 0; mf < 4; ++mf)
                    #pragma unroll
                    for (int c = 0; c < 3; ++c) {
                        a[mf][c]  = *(const short8b*)(lc + arow[mf] + c * 64);
                        bb[mf][c] = *(const short8b*)(lc + brow[mf] + c * 64);
                    }
                __syncthreads();   // all waves' reads done (lgkmcnt drained)

                // ---- issue next stage's async loads ----
                {
                    int h2 = h ^ 1, q2 = q, rt2 = rt;
                    if (h == 1) { q2 = q + 1; h2 = 0; if (q2 == 9) { q2 = 0; rt2 = rt + 1; } }
                    issue(rt2, q2, h2);
                }

                // ---- 6-product MFMA ----
                #pragma unroll
                for (int mf = 0; mf < 4; ++mf)
                    #pragma unroll
                    for (int nf = 0; nf < 4; ++nf) {
                        f32x4 d = acc[mf][nf];
                        d = __builtin_amdgcn_mfma_f32_16x16x32_bf16(a[mf][0], bb[nf][0], d, 0, 0, 0);
                        d = __builtin_amdgcn_mfma_f32_16x16x32_bf16(a[mf][0], bb[nf][1], d, 0, 0, 0);
                        d = __builtin_amdgcn_mfma_f32_16x16x32_bf16(a[mf][1], bb[nf][0], d, 0, 0, 0);
                        d = __builtin_amdgcn_mfma_f32_16x16x32_bf16(a[mf][1], bb[nf][1], d, 0, 0, 0);
                        d = __builtin_amdgcn_mfma_f32_16x16x32_bf16(a[mf][0], bb[nf][2], d, 0, 0, 0);
                        d = __builtin_amdgcn_mfma_f32_16x16x32_bf16(a[mf][2], bb[nf][0], d, 0, 0, 0);
                        acc[mf][nf] = d;
                    }
                __syncthreads();   // vmcnt(0): next stage landed in LDS
            }
        }

        // ---- epilogue: scale by invn_rs, max/argmax over this rt's 128 r ----
        #pragma unroll
        for (int nf = 0; nf < 4; ++nf) {
            float bv = -1e30f; int bi = 0;
            #pragma unroll
            for (int mf = 0; mf < 4; ++mf) {
                #pragma unroll
                for (int reg = 0; reg < 4; ++reg) {
                    int r = r0 + wr * 64 + mf * 16 + g * 4 + reg;
                    float val = acc[mf][nf][reg] * invn_rs[r];
                    if (val > bv || (val == bv && r < bi)) { bv = val; bi = r; }
                }
            }
            #pragma unroll
            for (int ofs = 16; ofs < 64; ofs <<= 1) {
                float ov = __shfl_xor(bv, ofs);
                int   oi = __shfl_xor(bi, ofs);
                if (ov > bv || (ov == bv && oi < bi)) { bv = ov; bi = oi; }
            }
            if (g == 0) {
                int col = wc * 64 + nf * 16 + ln;
                sm[wr * 128 + col] = bv;
                si[wr * 128 + col] = bi;
            }
        }
        __syncthreads();
        if (tid < 128) {
            float bm = run_m; int ba = run_a;
            #pragma unroll
            for (int ww = 0; ww < 2; ++ww) {
                float v = sm[ww * 128 + tid];
                int   a2 = si[ww * 128 + tid];
                if (v > bm || (v == bm && a2 < ba)) { bm = v; ba = a2; }
            }
            run_m = bm; run_a = ba;
        }
        __syncthreads();           // sm/si free for next rt
    }

    if (tid < 128) {
        int l = l0 + tid;
        int o = (b * SPLITS + blockIdx.y) * LL + l;
        ws[WS_PMAX + o] = run_m;
        ((int*)ws)[WS_PARG + o] = run_a;
    }
}

// -------- 4) reduce over splits -> s output + final argmax --------
__global__ void k_reduce(float* __restrict__ ws, float* __restrict__ out) {
    int t = blockIdx.x * 256 + threadIdx.x;   // 0..B*L-1
    int b = t >> 12;
    int l = t & (LL - 1);
    float bm = -1e30f; int ba = 0;
    for (int s = 0; s < SPLITS; ++s) {        // splits are ascending r ranges
        int o = (b * SPLITS + s) * LL + l;
        float v = ws[WS_PMAX + o];
        int   a = ((int*)ws)[WS_PARG + o];
        if (v > bm || (v == bm && a < ba)) { bm = v; ba = a; }
    }
    out[t] = bm * ws[WS_INV_LR + t];          // s: [B,1,H,W] flat
    ((int*)ws)[WS_ARG + t] = ba;
}

// -------- 5) gather from ref via argmax + fold(3x3, pad 1) --------
__global__ void k_fold(const float* __restrict__ ref,
                       const float* __restrict__ ws,
                       float* __restrict__ out) {
    int t = blockIdx.x * 256 + threadIdx.x;   // 0..B*C*L-1
    int b = t >> 18;
    int c = (t >> 12) & 63;
    int yx = t & (LL - 1);
    int y = yx >> 6, x = yx & 63;
    const int* ab = ((const int*)ws) + WS_ARG + b * LL;
    const float* rb = ref + (size_t)b * CH * LL + c * LL;
    float s = 0.f;
    #pragma unroll
    for (int i = 0; i < 3; ++i) {
        int yp = y + 1 - i;
        if ((unsigned)yp >= (unsigned)HH) continue;
        #pragma unroll
        for (int j = 0; j < 3; ++j) {
            int xp = x + 1 - j;
            if ((unsigned)xp >= (unsigned)WW) continue;
            int r = ab[yp * WW + xp];
            int ry = (r >> 6) + i - 1;
            int rx = (r & 63) + j - 1;
            if ((unsigned)ry < (unsigned)HH && (unsigned)rx < (unsigned)WW)
                s += rb[ry * WW + rx];
        }
    }
    out[BATCH * LL + t] = s;                  // trans after s (16384 floats)
}

extern "C" void kernel_launch(void* const* d_in, const int* in_sizes, int n_in,
                              void* d_out, int out_size, void* d_ws, size_t ws_size,
                              hipStream_t stream) {
    const float* lrsr = (const float*)d_in[0];
    const float* refsr = (const float*)d_in[1];
    const float* ref  = (const float*)d_in[2];
    float* out = (float*)d_out;
    float* ws  = (float*)d_ws;

    // zero the padded pre-split region (borders must be 0)
    hipMemsetAsync((char*)d_ws + GP_BYTE_BASE, 0, GP_TOTAL, stream);
    k_split<<<dim3(16, 8, 8), dim3(256), 0, stream>>>(lrsr, refsr, ws);
    k_ssq<<<dim3(BATCH * LL / 256), dim3(256), 0, stream>>>(lrsr, refsr, ws);
    k_inv<<<dim3(BATCH * LL / 256), dim3(256), 0, stream>>>(ws);
    k_corrmax<<<dim3(LL / BN, SPLITS, BATCH), dim3(256), 0, stream>>>(ws);
    k_reduce<<<dim3(BATCH * LL / 256), dim3(256), 0, stream>>>(ws, out);
    k_fold<<<dim3(BATCH * CH * LL / 256), dim3(256), 0, stream>>>(ref, ws, out);
}